// Round 12
// baseline (70.663 us; speedup 1.0000x reference)
//
#include <hip/hip_runtime.h>

#define OUT_F 16384
#define IN_F  4096
#define GS    128
#define NG    32
#define KTS   256          // ints per row per SUPER-tile (= 2 scale groups)
#define NST   16           // super-tiles covering full K

typedef __attribute__((ext_vector_type(4)))  int    int4v;
typedef __attribute__((ext_vector_type(4)))  float  float4v;
typedef __attribute__((ext_vector_type(8)))  short  short8v;
typedef __attribute__((ext_vector_type(16))) float  floatx16;

// f32 -> bf16 round-to-nearest-even (bit-level)
static __device__ __forceinline__ short f32_bf16_rne(float f) {
    unsigned u = __float_as_uint(f);
    u += 0x7FFFu + ((u >> 16) & 1u);
    return (short)(u >> 16);
}

// HBM -> LDS direct, 16B/lane; dest = wave-uniform base + lane*16 (HW rule)
#define GLOAD_LDS16(gp, lp)                                                    \
    __builtin_amdgcn_global_load_lds(                                          \
        (const __attribute__((address_space(1))) void*)(gp),                   \
        (__attribute__((address_space(3))) void*)(lp), 16, 0, 0)

// ---------------------------------------------------------------------------
// Pre-kernel: x B-fragments in MFMA layout (verified rounds 5-11).
// Lane l of chunk c holds x[b = l&31][k = c*16 + (l>>5)*8 + i], i=0..7.
// ---------------------------------------------------------------------------
__global__ void xfrag_kernel(const float* __restrict__ x, short* __restrict__ xf) {
    int gid = blockIdx.x * blockDim.x + threadIdx.x;  // 0..131071
    int i = gid & 7;
    int l = (gid >> 3) & 63;
    int c = gid >> 9;
    int b = l & 31;
    int k = c * 16 + (l >> 5) * 8 + i;
    xf[gid] = f32_bf16_rne(x[(size_t)b * IN_F + k]);
}

// ---------------------------------------------------------------------------
// Main kernel: 512 blocks x 1 wave; wave owns 32 rows x full K. All 512
// blocks co-resident (2/CU, 64 KB LDS each) -> zero tail.
// Super-tile [32 rows][256 ints] staged as 32 gload_lds of 1 KB, each from
// ONE row (max HBM burst). Source unit pre-swizzled u = l ^ (row&15) so LDS
// is XOR-swizzled; reads use the same involution. Double-buffered, one
// counted vmcnt(40) per super-tile -- queue never drains. bfrA consumed by
// sub-tile 0 then reloaded for T+1; bfrB likewise after sub-tile 1.
// No barriers, no cross-wave reduce; verified wave-local epilogue.
// ---------------------------------------------------------------------------
__global__ __launch_bounds__(64) void int4linear_mfma(
    const int* __restrict__ w, const float* __restrict__ scales,
    const float* __restrict__ bias, const short* __restrict__ xf,
    float* __restrict__ out)
{
    __shared__ int lds[2 * 32 * KTS];   // 64 KB double buffer

    const int l  = threadIdx.x;        // 0..63
    const int ll = l & 31;
    const int hl = l >> 5;
    const int o_base = blockIdx.x * 32;

    floatx16 acc = {};

    // staging addresses: op j (0..31) reads row j; lane l fetches 16B unit
    // u = l ^ (j&15), so linear LDS write leaves LDS[j][slot s] = unit s^(j&15).
    int goff[32];
#pragma unroll
    for (int j = 0; j < 32; ++j)
        goff[j] = (o_base + j) * IN_F + ((l ^ (j & 15)) << 2);

    // all 32 group-scales for this lane's output row (no per-tile VMEM)
    float scv[32];
    {
        const float* sp = scales + (size_t)(o_base + ll) * NG;
#pragma unroll
        for (int j = 0; j < 8; ++j) {
            float4v v = *(const float4v*)(sp + 4 * j);
            scv[4 * j + 0] = v[0]; scv[4 * j + 1] = v[1];
            scv[4 * j + 2] = v[2]; scv[4 * j + 3] = v[3];
        }
    }

    short8v bfrA[8], bfrB[8];

    // ---- prologue: stage super-tile 0 + its 16 xf chunks ----
#pragma unroll
    for (int j = 0; j < 32; ++j)
        GLOAD_LDS16(w + goff[j], &lds[j * 256]);
#pragma unroll
    for (int ch = 0; ch < 8; ++ch)
        bfrA[ch] = *(const short8v*)(xf + (size_t)ch * 512 + l * 8);
#pragma unroll
    for (int ch = 0; ch < 8; ++ch)
        bfrB[ch] = *(const short8v*)(xf + (size_t)(8 + ch) * 512 + l * 8);

#pragma unroll
    for (int T = 0; T < NST; ++T) {
        const int rbuf = (T & 1) * 8192;
        const int wbuf = ((T + 1) & 1) * 8192;

        if (T + 1 < NST) {
            // 32x 1KB single-row staging for super-tile T+1
#pragma unroll
            for (int j = 0; j < 32; ++j)
                GLOAD_LDS16(w + goff[j] + (T + 1) * KTS, &lds[wbuf + j * 256]);
            // newest 40 = stg(T+1)32 + xfB(T)8 stay; stg(T)+xfA(T) drained
            asm volatile("s_waitcnt vmcnt(40)" ::: "memory");
        } else {
            asm volatile("s_waitcnt vmcnt(0)" ::: "memory");
        }
        __builtin_amdgcn_sched_barrier(0);

        // ---- sub-tile 0: chunks 0..7, scale group 2T ----
        {
            const float sc = scv[2 * T];
#pragma unroll
            for (int ch = 0; ch < 8; ++ch) {
                const int u0 = ch * 4 + hl * 2;
                const int4v qa = *(const int4v*)&lds[rbuf + ll * 256 + (((u0    ) ^ (ll & 15)) << 2)];
                const int4v qb = *(const int4v*)&lds[rbuf + ll * 256 + (((u0 + 1) ^ (ll & 15)) << 2)];
                short8v af;
                af[0] = f32_bf16_rne((float)qa[0] * sc);
                af[1] = f32_bf16_rne((float)qa[1] * sc);
                af[2] = f32_bf16_rne((float)qa[2] * sc);
                af[3] = f32_bf16_rne((float)qa[3] * sc);
                af[4] = f32_bf16_rne((float)qb[0] * sc);
                af[5] = f32_bf16_rne((float)qb[1] * sc);
                af[6] = f32_bf16_rne((float)qb[2] * sc);
                af[7] = f32_bf16_rne((float)qb[3] * sc);
                acc = __builtin_amdgcn_mfma_f32_32x32x16_bf16(af, bfrA[ch], acc, 0, 0, 0);
            }
        }
        // reload bfrA for T+1 (bfrA dead after sub-tile 0)
        if (T + 1 < NST) {
#pragma unroll
            for (int ch = 0; ch < 8; ++ch)
                bfrA[ch] = *(const short8v*)(xf + (size_t)((T + 1) * 16 + ch) * 512 + l * 8);
        }

        // ---- sub-tile 1: chunks 8..15, scale group 2T+1 ----
        {
            const float sc = scv[2 * T + 1];
#pragma unroll
            for (int ch = 8; ch < 16; ++ch) {
                const int u0 = ch * 4 + hl * 2;
                const int4v qa = *(const int4v*)&lds[rbuf + ll * 256 + (((u0    ) ^ (ll & 15)) << 2)];
                const int4v qb = *(const int4v*)&lds[rbuf + ll * 256 + (((u0 + 1) ^ (ll & 15)) << 2)];
                short8v af;
                af[0] = f32_bf16_rne((float)qa[0] * sc);
                af[1] = f32_bf16_rne((float)qa[1] * sc);
                af[2] = f32_bf16_rne((float)qa[2] * sc);
                af[3] = f32_bf16_rne((float)qa[3] * sc);
                af[4] = f32_bf16_rne((float)qb[0] * sc);
                af[5] = f32_bf16_rne((float)qb[1] * sc);
                af[6] = f32_bf16_rne((float)qb[2] * sc);
                af[7] = f32_bf16_rne((float)qb[3] * sc);
                acc = __builtin_amdgcn_mfma_f32_32x32x16_bf16(af, bfrB[ch - 8], acc, 0, 0, 0);
            }
        }
        // reload bfrB for T+1 (bfrB dead after sub-tile 1)
        if (T + 1 < NST) {
#pragma unroll
            for (int ch = 0; ch < 8; ++ch)
                bfrB[ch] = *(const short8v*)(xf + (size_t)((T + 1) * 16 + 8 + ch) * 512 + l * 8);
        }
    }

    // ---- wave-local epilogue (verified): XOR transpose -> coalesced stores
    float* lf = (float*)lds;   // buffer 0 region; final tile read from buffer 1
#pragma unroll
    for (int r = 0; r < 16; ++r) {
        // C/D layout (verified): b = lane&31, o = (r&3)+8*(r>>2)+4*(lane>>5)
        int o = (r & 3) + 8 * (r >> 2) + 4 * hl;
        lf[o * 32 + (ll ^ o)] = acc[r];     // conflict-free (XOR bijection)
    }
    asm volatile("s_waitcnt lgkmcnt(0)" ::: "memory");
    __builtin_amdgcn_sched_barrier(0);

    const float bv = bias[o_base + ll];
#pragma unroll
    for (int i = 0; i < 16; ++i) {
        int b = 2 * i + hl;
        float v = lf[ll * 32 + (b ^ ll)];   // conflict-free
        out[(size_t)b * OUT_F + o_base + ll] = v + bv;  // 128B runs, coalesced
    }
}

extern "C" void kernel_launch(void* const* d_in, const int* in_sizes, int n_in,
                              void* d_out, int out_size, void* d_ws, size_t ws_size,
                              hipStream_t stream) {
    const float* x      = (const float*)d_in[0];
    const int*   w      = (const int*)d_in[1];
    const float* scales = (const float*)d_in[2];
    const float* bias   = (const float*)d_in[3];
    float*       out    = (float*)d_out;
    short*       xfrag  = (short*)d_ws;  // 256 KB fragment buffer

    hipLaunchKernelGGL(xfrag_kernel, dim3(512), dim3(256), 0, stream, x, xfrag);
    hipLaunchKernelGGL(int4linear_mfma, dim3(OUT_F / 32), dim3(64), 0, stream,
                       w, scales, bias, xfrag, out);
}

// Round 14
// 50.574 us; speedup vs baseline: 1.3972x; 1.3972x over previous
//
#include <hip/hip_runtime.h>

#define OUT_F 16384
#define IN_F  4096
#define GS    128
#define NG    32
#define KT    64           // ints per row per K-tile (= GS/2)
#define NTW   16           // tiles per wave (quarter-K: 1024 ints / KT)

typedef __attribute__((ext_vector_type(4)))  int    int4v;
typedef __attribute__((ext_vector_type(4)))  float  float4v;
typedef __attribute__((ext_vector_type(8)))  short  short8v;
typedef __attribute__((ext_vector_type(16))) float  floatx16;

// f32 -> bf16 round-to-nearest-even (bit-level)
static __device__ __forceinline__ short f32_bf16_rne(float f) {
    unsigned u = __float_as_uint(f);
    u += 0x7FFFu + ((u >> 16) & 1u);
    return (short)(u >> 16);
}

// HBM -> LDS direct, 16B/lane; dest = wave-uniform base + lane*16 (HW rule)
#define GLOAD_LDS16(gp, lp)                                                    \
    __builtin_amdgcn_global_load_lds(                                          \
        (const __attribute__((address_space(1))) void*)(gp),                   \
        (__attribute__((address_space(3))) void*)(lp), 16, 0, 0)

// ---------------------------------------------------------------------------
// Pre-kernel: x B-fragments in MFMA layout (verified rounds 5-12).
// Lane l of chunk c holds x[b = l&31][k = c*16 + (l>>5)*8 + i], i=0..7.
// ---------------------------------------------------------------------------
__global__ void xfrag_kernel(const float* __restrict__ x, short* __restrict__ xf) {
    int gid = blockIdx.x * blockDim.x + threadIdx.x;  // 0..131071
    int i = gid & 7;
    int l = (gid >> 3) & 63;
    int c = gid >> 9;
    int b = l & 31;
    int k = c * 16 + (l >> 5) * 8 + i;
    xf[gid] = f32_bf16_rne(x[(size_t)b * IN_F + k]);
}

// ---------------------------------------------------------------------------
// Main kernel: 512 blocks x 4 waves -> 64 KB LDS -> 2 blocks/CU -> 8 waves/CU.
// Wave wv owns 32 rows x quarter-K: 16 tiles of [32 rows][64 ints].
// Per tile: 8x gload_lds (1 KB each, 4 rows x 256 B, source pre-swizzled
// u = (l&15) ^ (row&15)), xf prefetched ONE TILE AHEAD (bfrA/bfrB parity),
// counted vmcnt(12). No main-loop barriers.
// RACE-FREE epilogue (r13 bug fix): every wave writes partials ONLY inside
// its own 16 KB region; wave 0 reads them after the single __syncthreads.
// ---------------------------------------------------------------------------
__global__ __launch_bounds__(256) void int4linear_mfma(
    const int* __restrict__ w, const float* __restrict__ scales,
    const float* __restrict__ bias, const short* __restrict__ xf,
    float* __restrict__ out)
{
    __shared__ int lds[16384];         // 64 KB: wave wv owns [wv*4096, +4096)

    const int tid = threadIdx.x;
    const int wv  = tid >> 6;          // 0..3
    const int l   = tid & 63;
    const int ll  = l & 31;
    const int hl  = l >> 5;
    const int o_base = blockIdx.x * 32;

    floatx16 acc = {};
    int* mylds = lds + wv * 4096;

    // staging: instr j covers rows 4j..4j+3 (lane l -> row 4j + (l>>4),
    // source unit (l&15) ^ (row&15)); linear LDS dest j*1KB.
    int goff[8];
#pragma unroll
    for (int j = 0; j < 8; ++j) {
        int r = 4 * j + (l >> 4);
        goff[j] = (o_base + r) * IN_F + wv * 1024 + (((l & 15) ^ (r & 15)) << 2);
    }

    // this wave's 8 group-scales for row ll (quarter-K = 8 groups)
    float scv[8];
    {
        const float* sp = scales + (size_t)(o_base + ll) * NG + wv * 8;
#pragma unroll
        for (int j = 0; j < 2; ++j) {
            float4v v = *(const float4v*)(sp + 4 * j);
            scv[4 * j + 0] = v[0]; scv[4 * j + 1] = v[1];
            scv[4 * j + 2] = v[2]; scv[4 * j + 3] = v[3];
        }
    }

    const short* xfw = xf + (size_t)(wv * 64) * 512;   // wave's chunk base

    short8v bfrA[4], bfrB[4];

    // ---- prologue: stage tile 0 + xf tile 0 ----
#pragma unroll
    for (int j = 0; j < 8; ++j)
        GLOAD_LDS16(w + goff[j], &mylds[j * 256]);
#pragma unroll
    for (int ch = 0; ch < 4; ++ch)
        bfrA[ch] = *(const short8v*)(xfw + (size_t)ch * 512 + l * 8);

#pragma unroll
    for (int t = 0; t < NTW; ++t) {
        const int rbuf = (t & 1) * 2048;
        const int wbuf = ((t + 1) & 1) * 2048;

        if (t + 1 < NTW) {
            // next tile's staging, then next tile's xf (prefetch)
#pragma unroll
            for (int j = 0; j < 8; ++j)
                GLOAD_LDS16(w + goff[j] + (t + 1) * KT, &mylds[wbuf + j * 256]);
#pragma unroll
            for (int ch = 0; ch < 4; ++ch) {
                short8v v = *(const short8v*)(xfw + (size_t)((t + 1) * 4 + ch) * 512 + l * 8);
                if (t & 1) bfrA[ch] = v; else bfrB[ch] = v;
            }
            // drain exactly last iteration's 12 ops (issued a full tile ago);
            // keep the newest 12 (staging t+1 + xf t+1) in flight.
            asm volatile("s_waitcnt vmcnt(12)" ::: "memory");
        } else {
            asm volatile("s_waitcnt vmcnt(0)" ::: "memory");
        }
        __builtin_amdgcn_sched_barrier(0);

        // tile t spans half a scale group: group = t>>1 (KT = GS/2)
        const float sc = scv[t >> 1];

#pragma unroll
        for (int ch = 0; ch < 4; ++ch) {
            const int u0 = ch * 4 + hl * 2;   // logical 16B-unit 0..15
            const int4v qa = *(const int4v*)&mylds[rbuf + ll * 64 + (((u0    ) ^ (ll & 15)) << 2)];
            const int4v qb = *(const int4v*)&mylds[rbuf + ll * 64 + (((u0 + 1) ^ (ll & 15)) << 2)];
            const short8v bf = (t & 1) ? bfrB[ch] : bfrA[ch];

            short8v af;
            af[0] = f32_bf16_rne((float)qa[0] * sc);
            af[1] = f32_bf16_rne((float)qa[1] * sc);
            af[2] = f32_bf16_rne((float)qa[2] * sc);
            af[3] = f32_bf16_rne((float)qa[3] * sc);
            af[4] = f32_bf16_rne((float)qb[0] * sc);
            af[5] = f32_bf16_rne((float)qb[1] * sc);
            af[6] = f32_bf16_rne((float)qb[2] * sc);
            af[7] = f32_bf16_rne((float)qb[3] * sc);

            acc = __builtin_amdgcn_mfma_f32_32x32x16_bf16(af, bf, acc, 0, 0, 0);
        }
    }

    // ---- RACE-FREE epilogue: partials stay inside each wave's own region ---
    // wave wv>0: store acc at float offset wv*4096 (own region, own DMAs
    // already drained by this wave's final vmcnt(0); nobody else writes here).
    if (wv > 0) {
        float* myred = (float*)lds + wv * 4096;
#pragma unroll
        for (int r = 0; r < 16; ++r)
            myred[l * 16 + r] = acc[r];
    }
    __syncthreads();
    if (wv == 0) {
        const float* lfp = (const float*)lds;
#pragma unroll
        for (int r = 0; r < 16; ++r)
            acc[r] += lfp[4096 + l * 16 + r] + lfp[8192 + l * 16 + r]
                    + lfp[12288 + l * 16 + r];

        float* lf = (float*)lds + 3072;   // wave 0's own region, floats 3072..4096
#pragma unroll
        for (int r = 0; r < 16; ++r) {
            // C/D layout (verified): b = lane&31, o = (r&3)+8*(r>>2)+4*(lane>>5)
            int o = (r & 3) + 8 * (r >> 2) + 4 * hl;
            lf[o * 32 + (ll ^ o)] = acc[r]; // conflict-free (XOR bijection)
        }
        asm volatile("s_waitcnt lgkmcnt(0)" ::: "memory");
        __builtin_amdgcn_sched_barrier(0);

        const float bv = bias[o_base + ll];
#pragma unroll
        for (int i = 0; i < 16; ++i) {
            int b = 2 * i + hl;
            float v = lf[ll * 32 + (b ^ ll)];              // conflict-free
            out[(size_t)b * OUT_F + o_base + ll] = v + bv; // 128B-coalesced
        }
    }
}

extern "C" void kernel_launch(void* const* d_in, const int* in_sizes, int n_in,
                              void* d_out, int out_size, void* d_ws, size_t ws_size,
                              hipStream_t stream) {
    const float* x      = (const float*)d_in[0];
    const int*   w      = (const int*)d_in[1];
    const float* scales = (const float*)d_in[2];
    const float* bias   = (const float*)d_in[3];
    float*       out    = (float*)d_out;
    short*       xfrag  = (short*)d_ws;  // 256 KB fragment buffer

    hipLaunchKernelGGL(xfrag_kernel, dim3(512), dim3(256), 0, stream, x, xfrag);
    hipLaunchKernelGGL(int4linear_mfma, dim3(OUT_F / 32), dim3(256), 0, stream,
                       w, scales, bias, xfrag, out);
}